// Round 1
// baseline (398.264 us; speedup 1.0000x reference)
//
#include <hip/hip_runtime.h>
#include <math.h>

// Problem constants
#define BSZ    2
#define LSEQ   2048
#define DI     2048
#define DSTATE 8
#define DTRANK 256
#define KXP    (DTRANK + 2 * DSTATE)   // 272
#define NC     16                      // scan chunks
#define CL     (LSEQ / NC)             // 128

// ---------------------------------------------------------------------------
// GEMM1: xdbl[4096,272] = x[4096,2048] @ W_xproj^T   (W_xproj is [272,2048])
// 64x64 tile, BK=16, 256 threads, 4x4 micro-tile per thread.
// ---------------------------------------------------------------------------
__global__ __launch_bounds__(256) void gemm_xproj(const float* __restrict__ x,
                                                  const float* __restrict__ W,
                                                  float* __restrict__ xdbl) {
    const int K = DI;  // 2048
    __shared__ float As[16][68];
    __shared__ float Bs[16][68];
    const int t  = threadIdx.x;
    const int tx = t & 15, ty = t >> 4;
    const int m0 = blockIdx.y * 64;
    const int n0 = blockIdx.x * 64;
    const int lm = t >> 2;         // 0..63
    const int lk = (t & 3) * 4;    // 0,4,8,12
    const bool bvalid = (n0 + lm) < KXP;
    float acc[4][4] = {};

    for (int k0 = 0; k0 < K; k0 += 16) {
        float4 av = *(const float4*)&x[(size_t)(m0 + lm) * K + k0 + lk];
        float4 bv = make_float4(0.f, 0.f, 0.f, 0.f);
        if (bvalid) bv = *(const float4*)&W[(size_t)(n0 + lm) * K + k0 + lk];
        __syncthreads();
        As[lk + 0][lm] = av.x; As[lk + 1][lm] = av.y;
        As[lk + 2][lm] = av.z; As[lk + 3][lm] = av.w;
        Bs[lk + 0][lm] = bv.x; Bs[lk + 1][lm] = bv.y;
        Bs[lk + 2][lm] = bv.z; Bs[lk + 3][lm] = bv.w;
        __syncthreads();
#pragma unroll
        for (int kk = 0; kk < 16; kk++) {
            float4 a = *(const float4*)&As[kk][ty * 4];
            float4 b = *(const float4*)&Bs[kk][tx * 4];
            float ar[4] = {a.x, a.y, a.z, a.w};
            float br[4] = {b.x, b.y, b.z, b.w};
#pragma unroll
            for (int i = 0; i < 4; i++)
#pragma unroll
                for (int j = 0; j < 4; j++) acc[i][j] += ar[i] * br[j];
        }
    }
    const int col = n0 + tx * 4;
    if (col < KXP) {
#pragma unroll
        for (int i = 0; i < 4; i++) {
            const int row = m0 + ty * 4 + i;
            float4 v = make_float4(acc[i][0], acc[i][1], acc[i][2], acc[i][3]);
            *(float4*)&xdbl[(size_t)row * KXP + col] = v;
        }
    }
}

// ---------------------------------------------------------------------------
// GEMM2: delta[4096,2048] = softplus(xdbl[:, :256] @ W_dt^T + b_dt)
// (W_dt is [2048,256]); same tiling, K=256, all dims divide evenly.
// ---------------------------------------------------------------------------
__global__ __launch_bounds__(256) void gemm_delta(const float* __restrict__ xdbl,
                                                  const float* __restrict__ Wdt,
                                                  const float* __restrict__ bdt,
                                                  float* __restrict__ delta) {
    const int K = DTRANK;  // 256
    __shared__ float As[16][68];
    __shared__ float Bs[16][68];
    const int t  = threadIdx.x;
    const int tx = t & 15, ty = t >> 4;
    const int m0 = blockIdx.y * 64;
    const int n0 = blockIdx.x * 64;
    const int lm = t >> 2;
    const int lk = (t & 3) * 4;
    float acc[4][4] = {};

    for (int k0 = 0; k0 < K; k0 += 16) {
        float4 av = *(const float4*)&xdbl[(size_t)(m0 + lm) * KXP + k0 + lk];
        float4 bv = *(const float4*)&Wdt[(size_t)(n0 + lm) * K + k0 + lk];
        __syncthreads();
        As[lk + 0][lm] = av.x; As[lk + 1][lm] = av.y;
        As[lk + 2][lm] = av.z; As[lk + 3][lm] = av.w;
        Bs[lk + 0][lm] = bv.x; Bs[lk + 1][lm] = bv.y;
        Bs[lk + 2][lm] = bv.z; Bs[lk + 3][lm] = bv.w;
        __syncthreads();
#pragma unroll
        for (int kk = 0; kk < 16; kk++) {
            float4 a = *(const float4*)&As[kk][ty * 4];
            float4 b = *(const float4*)&Bs[kk][tx * 4];
            float ar[4] = {a.x, a.y, a.z, a.w};
            float br[4] = {b.x, b.y, b.z, b.w};
#pragma unroll
            for (int i = 0; i < 4; i++)
#pragma unroll
                for (int j = 0; j < 4; j++) acc[i][j] += ar[i] * br[j];
        }
    }
    const int col = n0 + tx * 4;
    const float bd[4] = {bdt[col], bdt[col + 1], bdt[col + 2], bdt[col + 3]};
#pragma unroll
    for (int i = 0; i < 4; i++) {
        const int row = m0 + ty * 4 + i;
        float v[4];
#pragma unroll
        for (int j = 0; j < 4; j++) {
            float z = acc[i][j] + bd[j];
            v[j] = (z > 20.0f) ? z : log1pf(expf(z));  // softplus, stable
        }
        *(float4*)&delta[(size_t)row * DI + col] = make_float4(v[0], v[1], v[2], v[3]);
    }
}

// ---------------------------------------------------------------------------
// Scan pass 1: per (b, chunk, d) compute chunk summary (P = prod dA, H = h_end)
// starting from h = 0.
// grid: BSZ*NC*(DI/256) = 256 blocks x 256 threads
// ---------------------------------------------------------------------------
__global__ __launch_bounds__(256) void scan_pass1(const float* __restrict__ x,
                                                  const float* __restrict__ delta,
                                                  const float* __restrict__ xdbl,
                                                  const float* __restrict__ Alog,
                                                  float* __restrict__ Pb,
                                                  float* __restrict__ Hb) {
    const int bi   = blockIdx.x;
    const int b    = bi >> 7;          // /(NC*8)
    const int c    = (bi >> 3) & 15;
    const int dblk = bi & 7;
    const int d    = dblk * 256 + threadIdx.x;

    float A[8], h[8], P[8];
#pragma unroll
    for (int n = 0; n < 8; n++) {
        A[n] = -__expf(Alog[d * 8 + n]);
        h[n] = 0.f;
        P[n] = 1.f;
    }
    const int l0 = c * CL;
    for (int l = l0; l < l0 + CL; l++) {
        const size_t row = (size_t)b * LSEQ + l;
        const float dl = delta[row * DI + d];
        const float xv = x[row * DI + d];
        const float du = dl * xv;
        const float* Bp = &xdbl[row * KXP + DTRANK];
        const float4 B0 = *(const float4*)Bp;
        const float4 B1 = *(const float4*)(Bp + 4);
        const float Bn[8] = {B0.x, B0.y, B0.z, B0.w, B1.x, B1.y, B1.z, B1.w};
#pragma unroll
        for (int n = 0; n < 8; n++) {
            const float dA = __expf(dl * A[n]);
            h[n] = dA * h[n] + du * Bn[n];
            P[n] *= dA;
        }
    }
    const size_t base = ((size_t)(b * NC + c) * DI + d) * 8;
    *(float4*)&Pb[base]     = make_float4(P[0], P[1], P[2], P[3]);
    *(float4*)&Pb[base + 4] = make_float4(P[4], P[5], P[6], P[7]);
    *(float4*)&Hb[base]     = make_float4(h[0], h[1], h[2], h[3]);
    *(float4*)&Hb[base + 4] = make_float4(h[4], h[5], h[6], h[7]);
}

// ---------------------------------------------------------------------------
// Scan pass 2: sequentially combine the NC chunk summaries per (b,d) to
// produce h0[b,c,d,:] = state entering chunk c.
// grid: BSZ*DI/256 = 32 blocks (wait: 2*2048/256 = 16) x 256 threads
// ---------------------------------------------------------------------------
__global__ __launch_bounds__(256) void scan_pass2(const float* __restrict__ Pb,
                                                  const float* __restrict__ Hb,
                                                  float* __restrict__ h0) {
    const int t = blockIdx.x * 256 + threadIdx.x;  // 0..4095
    const int b = t >> 11;
    const int d = t & (DI - 1);
    float h[8] = {0.f, 0.f, 0.f, 0.f, 0.f, 0.f, 0.f, 0.f};
    for (int c = 0; c < NC; c++) {
        const size_t base = ((size_t)(b * NC + c) * DI + d) * 8;
        *(float4*)&h0[base]     = make_float4(h[0], h[1], h[2], h[3]);
        *(float4*)&h0[base + 4] = make_float4(h[4], h[5], h[6], h[7]);
        const float4 p0 = *(const float4*)&Pb[base];
        const float4 p1 = *(const float4*)&Pb[base + 4];
        const float4 q0 = *(const float4*)&Hb[base];
        const float4 q1 = *(const float4*)&Hb[base + 4];
        const float P[8] = {p0.x, p0.y, p0.z, p0.w, p1.x, p1.y, p1.z, p1.w};
        const float H[8] = {q0.x, q0.y, q0.z, q0.w, q1.x, q1.y, q1.z, q1.w};
#pragma unroll
        for (int n = 0; n < 8; n++) h[n] = P[n] * h[n] + H[n];
    }
}

// ---------------------------------------------------------------------------
// Scan pass 3: re-scan each chunk from h0, produce y.
// grid: 256 blocks x 256 threads (same mapping as pass 1)
// ---------------------------------------------------------------------------
__global__ __launch_bounds__(256) void scan_pass3(const float* __restrict__ x,
                                                  const float* __restrict__ delta,
                                                  const float* __restrict__ xdbl,
                                                  const float* __restrict__ Alog,
                                                  const float* __restrict__ Dp,
                                                  const float* __restrict__ h0,
                                                  float* __restrict__ y) {
    const int bi   = blockIdx.x;
    const int b    = bi >> 7;
    const int c    = (bi >> 3) & 15;
    const int dblk = bi & 7;
    const int d    = dblk * 256 + threadIdx.x;

    float A[8], h[8];
    const size_t hbase = ((size_t)(b * NC + c) * DI + d) * 8;
    const float4 h0a = *(const float4*)&h0[hbase];
    const float4 h0b = *(const float4*)&h0[hbase + 4];
    h[0] = h0a.x; h[1] = h0a.y; h[2] = h0a.z; h[3] = h0a.w;
    h[4] = h0b.x; h[5] = h0b.y; h[6] = h0b.z; h[7] = h0b.w;
#pragma unroll
    for (int n = 0; n < 8; n++) A[n] = -__expf(Alog[d * 8 + n]);
    const float Dpar = Dp[d];

    const int l0 = c * CL;
    for (int l = l0; l < l0 + CL; l++) {
        const size_t row = (size_t)b * LSEQ + l;
        const float dl = delta[row * DI + d];
        const float xv = x[row * DI + d];
        const float du = dl * xv;
        const float* Bp = &xdbl[row * KXP + DTRANK];
        const float4 B0 = *(const float4*)Bp;
        const float4 B1 = *(const float4*)(Bp + 4);
        const float4 C0 = *(const float4*)(Bp + 8);
        const float4 C1 = *(const float4*)(Bp + 12);
        const float Bn[8] = {B0.x, B0.y, B0.z, B0.w, B1.x, B1.y, B1.z, B1.w};
        const float Cn[8] = {C0.x, C0.y, C0.z, C0.w, C1.x, C1.y, C1.z, C1.w};
        float yv = 0.f;
#pragma unroll
        for (int n = 0; n < 8; n++) {
            const float dA = __expf(dl * A[n]);
            h[n] = dA * h[n] + du * Bn[n];
            yv += h[n] * Cn[n];
        }
        yv += xv * Dpar;
        y[row * DI + d] = yv;
    }
}

// ---------------------------------------------------------------------------
extern "C" void kernel_launch(void* const* d_in, const int* in_sizes, int n_in,
                              void* d_out, int out_size, void* d_ws, size_t ws_size,
                              hipStream_t stream) {
    const float* x    = (const float*)d_in[0];
    const float* Wx   = (const float*)d_in[1];
    const float* Wdt  = (const float*)d_in[2];
    const float* bdt  = (const float*)d_in[3];
    const float* Alog = (const float*)d_in[4];
    const float* Dp   = (const float*)d_in[5];
    float* y = (float*)d_out;

    float* ws    = (float*)d_ws;
    float* xdbl  = ws;                                       // 4096*272
    float* delta = xdbl + (size_t)4096 * KXP;                // 4096*2048
    float* Pb    = delta + (size_t)4096 * DI;                // 2*16*2048*8
    float* Hb    = Pb + (size_t)BSZ * NC * DI * 8;
    float* h0    = Hb + (size_t)BSZ * NC * DI * 8;

    dim3 blk(256);
    hipLaunchKernelGGL(gemm_xproj, dim3(5, 64), blk, 0, stream, x, Wx, xdbl);
    hipLaunchKernelGGL(gemm_delta, dim3(32, 64), blk, 0, stream, xdbl, Wdt, bdt, delta);
    hipLaunchKernelGGL(scan_pass1, dim3(256), blk, 0, stream, x, delta, xdbl, Alog, Pb, Hb);
    hipLaunchKernelGGL(scan_pass2, dim3(16), blk, 0, stream, Pb, Hb, h0);
    hipLaunchKernelGGL(scan_pass3, dim3(256), blk, 0, stream, x, delta, xdbl, Alog, Dp, h0, y);
}

// Round 2
// 277.740 us; speedup vs baseline: 1.4339x; 1.4339x over previous
//
#include <hip/hip_runtime.h>
#include <math.h>

// Problem constants
#define BSZ    2
#define LSEQ   2048
#define DI     2048
#define DSTATE 8
#define DTRANK 256
#define KXP    (DTRANK + 2 * DSTATE)   // 272
#define NPAD   288                     // KXP padded to 18*16 for MFMA tiles
#define NC     16                      // scan chunks
#define CL     (LSEQ / NC)             // 128
#define KSPLIT 8

typedef __attribute__((ext_vector_type(8))) short bf16x8;
typedef __attribute__((ext_vector_type(4))) float f32x4;

static __device__ __forceinline__ unsigned short f2bf(float f) {
    unsigned u = __float_as_uint(f);
    u += 0x7fff + ((u >> 16) & 1);   // round-to-nearest-even
    return (unsigned short)(u >> 16);
}

// ---------------------------------------------------------------------------
// Convert fp32 inputs to bf16: x (8.4M), W_xproj (272x2048 -> padded 288x2048),
// W_dt (2048x256). One grid-stride-free flat kernel, 4 elems/thread.
// ---------------------------------------------------------------------------
#define NX   (4096u * 2048u)           // 8388608
#define NWXP (288u * 2048u)            // 589824 (padded)
#define NWX  (272u * 2048u)            // 557056 (real)
#define NWDT (2048u * 256u)            // 524288
__global__ __launch_bounds__(256) void convert_kern(const float* __restrict__ x,
                                                    const float* __restrict__ Wx,
                                                    const float* __restrict__ Wdt,
                                                    unsigned short* __restrict__ xb,
                                                    unsigned short* __restrict__ Wxb,
                                                    unsigned short* __restrict__ Wdtb) {
    const unsigned tid = blockIdx.x * 256 + threadIdx.x;
    const unsigned i4 = tid * 4;
    float4 v;
    unsigned short* dst;
    unsigned j;
    if (i4 < NX) {
        v = *(const float4*)&x[i4];
        dst = xb; j = i4;
    } else if (i4 < NX + NWXP) {
        j = i4 - NX;
        v = (j < NWX) ? *(const float4*)&Wx[j] : make_float4(0.f, 0.f, 0.f, 0.f);
        dst = Wxb;
    } else {
        j = i4 - (NX + NWXP);
        if (j >= NWDT) return;
        v = *(const float4*)&Wdt[j];
        dst = Wdtb;
    }
    ushort4 o;
    o.x = f2bf(v.x); o.y = f2bf(v.y); o.z = f2bf(v.z); o.w = f2bf(v.w);
    *(ushort4*)&dst[j] = o;
}

// ---------------------------------------------------------------------------
// GEMM1 (MFMA, split-K): part[ks][4096][288] = xb[., ks-chunk] @ Wxb^T
// grid (32 Mtiles, 8 Ksplits), 256 threads = 4 waves; wave owns 32 rows x 288
// cols = 2x18 fragments of 16x16. B-frags direct from global (L2-resident W).
// ---------------------------------------------------------------------------
__global__ __launch_bounds__(256, 1) void gemm1_mfma(const unsigned short* __restrict__ xb,
                                                     const unsigned short* __restrict__ Wxb,
                                                     float* __restrict__ part) {
    const int mt   = blockIdx.x;
    const int ks   = blockIdx.y;
    const int wave = threadIdx.x >> 6;
    const int lane = threadIdx.x & 63;
    const int quad = lane >> 4;
    const int r    = lane & 15;
    const int kq   = quad * 8;
    const int mbase = mt * 128 + wave * 32;
    const size_t arow0 = (size_t)(mbase + r) * DI;
    const size_t arow1 = (size_t)(mbase + 16 + r) * DI;
    const size_t brow  = (size_t)r * DI;

    f32x4 acc[2][18];
#pragma unroll
    for (int f = 0; f < 2; f++)
#pragma unroll
        for (int n = 0; n < 18; n++) acc[f][n] = (f32x4)(0.0f);

    const int kbeg = ks * (DI / KSPLIT);
#pragma unroll 2
    for (int k0 = kbeg; k0 < kbeg + DI / KSPLIT; k0 += 32) {
        const bf16x8 a0 = *(const bf16x8*)&xb[arow0 + k0 + kq];
        const bf16x8 a1 = *(const bf16x8*)&xb[arow1 + k0 + kq];
#pragma unroll
        for (int nf = 0; nf < 18; nf++) {
            const bf16x8 b = *(const bf16x8*)&Wxb[brow + nf * (16 * DI) + k0 + kq];
            acc[0][nf] = __builtin_amdgcn_mfma_f32_16x16x32_bf16(a0, b, acc[0][nf], 0, 0, 0);
            acc[1][nf] = __builtin_amdgcn_mfma_f32_16x16x32_bf16(a1, b, acc[1][nf], 0, 0, 0);
        }
    }

    float* p = part + (size_t)ks * 4096 * NPAD;
#pragma unroll
    for (int f = 0; f < 2; f++) {
        const int row0 = mbase + f * 16 + quad * 4;
#pragma unroll
        for (int nf = 0; nf < 18; nf++) {
            const int col = nf * 16 + r;
#pragma unroll
            for (int i = 0; i < 4; i++)
                p[(size_t)(row0 + i) * NPAD + col] = acc[f][nf][i];
        }
    }
}

// ---------------------------------------------------------------------------
// Reduce split-K partials -> xdbl fp32 [4096][272]; also emit dtr bf16
// [4096][256] (the dt_rank slice) for GEMM2. 4 cols/thread.
// ---------------------------------------------------------------------------
__global__ __launch_bounds__(256) void reduce1(const float* __restrict__ part,
                                               float* __restrict__ xdbl,
                                               unsigned short* __restrict__ dtr) {
    const int tid = blockIdx.x * 256 + threadIdx.x;  // 4096*72
    const int row = tid / 72;
    const int c4  = (tid - row * 72) * 4;
    float4 s = make_float4(0.f, 0.f, 0.f, 0.f);
#pragma unroll
    for (int ks = 0; ks < KSPLIT; ks++) {
        const float4 v = *(const float4*)&part[(size_t)ks * 4096 * NPAD + (size_t)row * NPAD + c4];
        s.x += v.x; s.y += v.y; s.z += v.z; s.w += v.w;
    }
    if (c4 < KXP) *(float4*)&xdbl[(size_t)row * KXP + c4] = s;
    if (c4 < DTRANK) {
        ushort4 o;
        o.x = f2bf(s.x); o.y = f2bf(s.y); o.z = f2bf(s.z); o.w = f2bf(s.w);
        *(ushort4*)&dtr[(size_t)row * DTRANK + c4] = o;
    }
}

// ---------------------------------------------------------------------------
// GEMM2 (MFMA): delta[4096][2048] = softplus(dtr @ Wdtb^T + b_dt), K=256.
// grid (16 Ntiles, 32 Mtiles); 128x128 block tile, 4 waves each 64x64
// (4x4 frags). Frags direct from global (both operands L2-resident).
// ---------------------------------------------------------------------------
__global__ __launch_bounds__(256, 2) void gemm2_mfma(const unsigned short* __restrict__ dtr,
                                                     const unsigned short* __restrict__ Wdtb,
                                                     const float* __restrict__ bdt,
                                                     float* __restrict__ delta) {
    const int nt   = blockIdx.x;
    const int mt   = blockIdx.y;
    const int wave = threadIdx.x >> 6;
    const int lane = threadIdx.x & 63;
    const int quad = lane >> 4;
    const int r    = lane & 15;
    const int kq   = quad * 8;
    const int mbase = mt * 128 + (wave >> 1) * 64;
    const int nbase = nt * 128 + (wave & 1) * 64;

    f32x4 acc[4][4];
#pragma unroll
    for (int f = 0; f < 4; f++)
#pragma unroll
        for (int g = 0; g < 4; g++) acc[f][g] = (f32x4)(0.0f);

#pragma unroll 2
    for (int k0 = 0; k0 < DTRANK; k0 += 32) {
        bf16x8 a[4], b[4];
#pragma unroll
        for (int f = 0; f < 4; f++)
            a[f] = *(const bf16x8*)&dtr[(size_t)(mbase + f * 16 + r) * DTRANK + k0 + kq];
#pragma unroll
        for (int g = 0; g < 4; g++)
            b[g] = *(const bf16x8*)&Wdtb[(size_t)(nbase + g * 16 + r) * DTRANK + k0 + kq];
#pragma unroll
        for (int f = 0; f < 4; f++)
#pragma unroll
            for (int g = 0; g < 4; g++)
                acc[f][g] = __builtin_amdgcn_mfma_f32_16x16x32_bf16(a[f], b[g], acc[f][g], 0, 0, 0);
    }

#pragma unroll
    for (int f = 0; f < 4; f++) {
        const int row0 = mbase + f * 16 + quad * 4;
#pragma unroll
        for (int g = 0; g < 4; g++) {
            const int col = nbase + g * 16 + r;
            const float bv = bdt[col];
#pragma unroll
            for (int i = 0; i < 4; i++) {
                const float z = acc[f][g][i] + bv;
                const float sp = (z > 20.0f) ? z : log1pf(__expf(z));
                delta[(size_t)(row0 + i) * DI + col] = sp;
            }
        }
    }
}

// ---------------------------------------------------------------------------
// Scan pass 1: per (b, chunk, d) chunk summary (P = prod dA, H = h_end), h=0.
// ---------------------------------------------------------------------------
__global__ __launch_bounds__(256) void scan_pass1(const float* __restrict__ x,
                                                  const float* __restrict__ delta,
                                                  const float* __restrict__ xdbl,
                                                  const float* __restrict__ Alog,
                                                  float* __restrict__ Pb,
                                                  float* __restrict__ Hb) {
    const int bi   = blockIdx.x;
    const int b    = bi >> 7;
    const int c    = (bi >> 3) & 15;
    const int dblk = bi & 7;
    const int d    = dblk * 256 + threadIdx.x;

    float A[8], h[8], P[8];
#pragma unroll
    for (int n = 0; n < 8; n++) {
        A[n] = -__expf(Alog[d * 8 + n]);
        h[n] = 0.f;
        P[n] = 1.f;
    }
    const int l0 = c * CL;
    for (int l = l0; l < l0 + CL; l++) {
        const size_t row = (size_t)b * LSEQ + l;
        const float dl = delta[row * DI + d];
        const float xv = x[row * DI + d];
        const float du = dl * xv;
        const float* Bp = &xdbl[row * KXP + DTRANK];
        const float4 B0 = *(const float4*)Bp;
        const float4 B1 = *(const float4*)(Bp + 4);
        const float Bn[8] = {B0.x, B0.y, B0.z, B0.w, B1.x, B1.y, B1.z, B1.w};
#pragma unroll
        for (int n = 0; n < 8; n++) {
            const float dA = __expf(dl * A[n]);
            h[n] = dA * h[n] + du * Bn[n];
            P[n] *= dA;
        }
    }
    const size_t base = ((size_t)(b * NC + c) * DI + d) * 8;
    *(float4*)&Pb[base]     = make_float4(P[0], P[1], P[2], P[3]);
    *(float4*)&Pb[base + 4] = make_float4(P[4], P[5], P[6], P[7]);
    *(float4*)&Hb[base]     = make_float4(h[0], h[1], h[2], h[3]);
    *(float4*)&Hb[base + 4] = make_float4(h[4], h[5], h[6], h[7]);
}

// ---------------------------------------------------------------------------
// Scan pass 2: combine NC chunk summaries per (b,d) -> h0 entering each chunk.
// ---------------------------------------------------------------------------
__global__ __launch_bounds__(256) void scan_pass2(const float* __restrict__ Pb,
                                                  const float* __restrict__ Hb,
                                                  float* __restrict__ h0) {
    const int t = blockIdx.x * 256 + threadIdx.x;  // 0..4095
    const int b = t >> 11;
    const int d = t & (DI - 1);
    float h[8] = {0.f, 0.f, 0.f, 0.f, 0.f, 0.f, 0.f, 0.f};
    for (int c = 0; c < NC; c++) {
        const size_t base = ((size_t)(b * NC + c) * DI + d) * 8;
        *(float4*)&h0[base]     = make_float4(h[0], h[1], h[2], h[3]);
        *(float4*)&h0[base + 4] = make_float4(h[4], h[5], h[6], h[7]);
        const float4 p0 = *(const float4*)&Pb[base];
        const float4 p1 = *(const float4*)&Pb[base + 4];
        const float4 q0 = *(const float4*)&Hb[base];
        const float4 q1 = *(const float4*)&Hb[base + 4];
        const float P[8] = {p0.x, p0.y, p0.z, p0.w, p1.x, p1.y, p1.z, p1.w};
        const float H[8] = {q0.x, q0.y, q0.z, q0.w, q1.x, q1.y, q1.z, q1.w};
#pragma unroll
        for (int n = 0; n < 8; n++) h[n] = P[n] * h[n] + H[n];
    }
}

// ---------------------------------------------------------------------------
// Scan pass 3: re-scan each chunk from h0, produce y.
// ---------------------------------------------------------------------------
__global__ __launch_bounds__(256) void scan_pass3(const float* __restrict__ x,
                                                  const float* __restrict__ delta,
                                                  const float* __restrict__ xdbl,
                                                  const float* __restrict__ Alog,
                                                  const float* __restrict__ Dp,
                                                  const float* __restrict__ h0,
                                                  float* __restrict__ y) {
    const int bi   = blockIdx.x;
    const int b    = bi >> 7;
    const int c    = (bi >> 3) & 15;
    const int dblk = bi & 7;
    const int d    = dblk * 256 + threadIdx.x;

    float A[8], h[8];
    const size_t hbase = ((size_t)(b * NC + c) * DI + d) * 8;
    const float4 h0a = *(const float4*)&h0[hbase];
    const float4 h0b = *(const float4*)&h0[hbase + 4];
    h[0] = h0a.x; h[1] = h0a.y; h[2] = h0a.z; h[3] = h0a.w;
    h[4] = h0b.x; h[5] = h0b.y; h[6] = h0b.z; h[7] = h0b.w;
#pragma unroll
    for (int n = 0; n < 8; n++) A[n] = -__expf(Alog[d * 8 + n]);
    const float Dpar = Dp[d];

    const int l0 = c * CL;
    for (int l = l0; l < l0 + CL; l++) {
        const size_t row = (size_t)b * LSEQ + l;
        const float dl = delta[row * DI + d];
        const float xv = x[row * DI + d];
        const float du = dl * xv;
        const float* Bp = &xdbl[row * KXP + DTRANK];
        const float4 B0 = *(const float4*)Bp;
        const float4 B1 = *(const float4*)(Bp + 4);
        const float4 C0 = *(const float4*)(Bp + 8);
        const float4 C1 = *(const float4*)(Bp + 12);
        const float Bn[8] = {B0.x, B0.y, B0.z, B0.w, B1.x, B1.y, B1.z, B1.w};
        const float Cn[8] = {C0.x, C0.y, C0.z, C0.w, C1.x, C1.y, C1.z, C1.w};
        float yv = 0.f;
#pragma unroll
        for (int n = 0; n < 8; n++) {
            const float dA = __expf(dl * A[n]);
            h[n] = dA * h[n] + du * Bn[n];
            yv += h[n] * Cn[n];
        }
        yv += xv * Dpar;
        y[row * DI + d] = yv;
    }
}

// ---------------------------------------------------------------------------
extern "C" void kernel_launch(void* const* d_in, const int* in_sizes, int n_in,
                              void* d_out, int out_size, void* d_ws, size_t ws_size,
                              hipStream_t stream) {
    const float* x    = (const float*)d_in[0];
    const float* Wx   = (const float*)d_in[1];
    const float* Wdt  = (const float*)d_in[2];
    const float* bdt  = (const float*)d_in[3];
    const float* Alog = (const float*)d_in[4];
    const float* Dp   = (const float*)d_in[5];
    float* y = (float*)d_out;

    // Workspace layout (delta aliases part: part dead after reduce1).
    float* part  = (float*)d_ws;                       // 8*4096*288 = 9437184 f
    float* delta = part;                               // 4096*2048  = 8388608 f (alias)
    float* xdbl  = part + (size_t)9437184;             // 1114112 f
    float* Pb    = xdbl + 1114112;                     // 524288 f
    float* Hb    = Pb + 524288;                        // 524288 f
    float* h0    = Hb + 524288;                        // 524288 f
    unsigned short* xb   = (unsigned short*)(h0 + 524288);  // 8388608 bf16
    unsigned short* Wxb  = xb + (size_t)NX;                 // 589824 bf16 (padded)
    unsigned short* Wdtb = Wxb + (size_t)NWXP;              // 524288 bf16
    unsigned short* dtr  = Wdtb + (size_t)NWDT;             // 1048576 bf16

    dim3 blk(256);
    hipLaunchKernelGGL(convert_kern, dim3((NX + NWXP + NWDT) / 4 / 256), blk, 0, stream,
                       x, Wx, Wdt, xb, Wxb, Wdtb);
    hipLaunchKernelGGL(gemm1_mfma, dim3(32, KSPLIT), blk, 0, stream, xb, Wxb, part);
    hipLaunchKernelGGL(reduce1, dim3(4096 * 72 / 256), blk, 0, stream, part, xdbl, dtr);
    hipLaunchKernelGGL(gemm2_mfma, dim3(16, 32), blk, 0, stream, dtr, Wdtb, bdt, delta);
    hipLaunchKernelGGL(scan_pass1, dim3(256), blk, 0, stream, x, delta, xdbl, Alog, Pb, Hb);
    hipLaunchKernelGGL(scan_pass2, dim3(16), blk, 0, stream, Pb, Hb, h0);
    hipLaunchKernelGGL(scan_pass3, dim3(256), blk, 0, stream, x, delta, xdbl, Alog, Dp, h0, y);
}

// Round 3
// 235.699 us; speedup vs baseline: 1.6897x; 1.1784x over previous
//
#include <hip/hip_runtime.h>
#include <math.h>

// Problem constants
#define BSZ    2
#define LSEQ   2048
#define DI     2048
#define DSTATE 8
#define DTRANK 256
#define KXP    (DTRANK + 2 * DSTATE)   // 272
#define NPAD   288                     // KXP padded to 18*16 for MFMA tiles
#define NC     32                      // scan chunks
#define CL     (LSEQ / NC)             // 64
#define KSPLIT 4

typedef __attribute__((ext_vector_type(8))) short bf16x8;
typedef __attribute__((ext_vector_type(4))) float f32x4;

static __device__ __forceinline__ unsigned short f2bf(float f) {
    unsigned u = __float_as_uint(f);
    u += 0x7fff + ((u >> 16) & 1);   // round-to-nearest-even
    return (unsigned short)(u >> 16);
}

// ---------------------------------------------------------------------------
// Convert fp32 inputs to bf16: x (8.4M), W_xproj (272x2048 -> padded 288x2048),
// W_dt (2048x256). Flat kernel, 4 elems/thread.
// ---------------------------------------------------------------------------
#define NX   (4096u * 2048u)           // 8388608
#define NWXP (288u * 2048u)            // 589824 (padded)
#define NWX  (272u * 2048u)            // 557056 (real)
#define NWDT (2048u * 256u)            // 524288
__global__ __launch_bounds__(256) void convert_kern(const float* __restrict__ x,
                                                    const float* __restrict__ Wx,
                                                    const float* __restrict__ Wdt,
                                                    unsigned short* __restrict__ xb,
                                                    unsigned short* __restrict__ Wxb,
                                                    unsigned short* __restrict__ Wdtb) {
    const unsigned tid = blockIdx.x * 256 + threadIdx.x;
    const unsigned i4 = tid * 4;
    float4 v;
    unsigned short* dst;
    unsigned j;
    if (i4 < NX) {
        v = *(const float4*)&x[i4];
        dst = xb; j = i4;
    } else if (i4 < NX + NWXP) {
        j = i4 - NX;
        v = (j < NWX) ? *(const float4*)&Wx[j] : make_float4(0.f, 0.f, 0.f, 0.f);
        dst = Wxb;
    } else {
        j = i4 - (NX + NWXP);
        if (j >= NWDT) return;
        v = *(const float4*)&Wdt[j];
        dst = Wdtb;
    }
    ushort4 o;
    o.x = f2bf(v.x); o.y = f2bf(v.y); o.z = f2bf(v.z); o.w = f2bf(v.w);
    *(ushort4*)&dst[j] = o;
}

// ---------------------------------------------------------------------------
// GEMM1 (MFMA, split-K): part[ks][4096][288] = xb[., ks-chunk] @ Wxb^T
// grid (64 Mtiles, 4 Ksplits) = 256 blocks; 4 waves, each 16 rows x 288 cols
// (1x18 frags). B-frags direct from global (W is L2-resident, shared by waves).
// ---------------------------------------------------------------------------
__global__ __launch_bounds__(256, 1) void gemm1_mfma(const unsigned short* __restrict__ xb,
                                                     const unsigned short* __restrict__ Wxb,
                                                     float* __restrict__ part) {
    const int mt   = blockIdx.x;   // 0..63
    const int ks   = blockIdx.y;   // 0..3
    const int wave = threadIdx.x >> 6;
    const int lane = threadIdx.x & 63;
    const int quad = lane >> 4;
    const int r    = lane & 15;
    const int kq   = quad * 8;
    const int mbase = mt * 64 + wave * 16;
    const size_t arow = (size_t)(mbase + r) * DI;
    const size_t brow = (size_t)r * DI;

    f32x4 acc[18];
#pragma unroll
    for (int n = 0; n < 18; n++) acc[n] = (f32x4)(0.0f);

    const int kbeg = ks * (DI / KSPLIT);
#pragma unroll 2
    for (int k0 = kbeg; k0 < kbeg + DI / KSPLIT; k0 += 32) {
        const bf16x8 a = *(const bf16x8*)&xb[arow + k0 + kq];
#pragma unroll
        for (int nf = 0; nf < 18; nf++) {
            const bf16x8 b = *(const bf16x8*)&Wxb[brow + nf * (16 * DI) + k0 + kq];
            acc[nf] = __builtin_amdgcn_mfma_f32_16x16x32_bf16(a, b, acc[nf], 0, 0, 0);
        }
    }

    float* p = part + (size_t)ks * 4096 * NPAD;
    const int row0 = mbase + quad * 4;
#pragma unroll
    for (int nf = 0; nf < 18; nf++) {
        const int col = nf * 16 + r;
#pragma unroll
        for (int i = 0; i < 4; i++)
            p[(size_t)(row0 + i) * NPAD + col] = acc[nf][i];
    }
}

// ---------------------------------------------------------------------------
// Reduce split-K partials -> xdbl fp32 [4096][272]; also emit dtr bf16
// [4096][256] for GEMM2. 4 cols/thread.
// ---------------------------------------------------------------------------
__global__ __launch_bounds__(256) void reduce1(const float* __restrict__ part,
                                               float* __restrict__ xdbl,
                                               unsigned short* __restrict__ dtr) {
    const int tid = blockIdx.x * 256 + threadIdx.x;  // 4096*72
    const int row = tid / 72;
    const int c4  = (tid - row * 72) * 4;
    float4 s = make_float4(0.f, 0.f, 0.f, 0.f);
#pragma unroll
    for (int ks = 0; ks < KSPLIT; ks++) {
        const float4 v = *(const float4*)&part[(size_t)ks * 4096 * NPAD + (size_t)row * NPAD + c4];
        s.x += v.x; s.y += v.y; s.z += v.z; s.w += v.w;
    }
    if (c4 < KXP) *(float4*)&xdbl[(size_t)row * KXP + c4] = s;
    if (c4 < DTRANK) {
        ushort4 o;
        o.x = f2bf(s.x); o.y = f2bf(s.y); o.z = f2bf(s.z); o.w = f2bf(s.w);
        *(ushort4*)&dtr[(size_t)row * DTRANK + c4] = o;
    }
}

// ---------------------------------------------------------------------------
// GEMM2 (MFMA): delta[4096][2048] = softplus(dtr @ Wdtb^T + b_dt), K=256.
// grid (16 Ntiles, 32 Mtiles); 128x128 block tile, 4 waves each 64x64.
// ---------------------------------------------------------------------------
__global__ __launch_bounds__(256, 2) void gemm2_mfma(const unsigned short* __restrict__ dtr,
                                                     const unsigned short* __restrict__ Wdtb,
                                                     const float* __restrict__ bdt,
                                                     float* __restrict__ delta) {
    const int nt   = blockIdx.x;
    const int mt   = blockIdx.y;
    const int wave = threadIdx.x >> 6;
    const int lane = threadIdx.x & 63;
    const int quad = lane >> 4;
    const int r    = lane & 15;
    const int kq   = quad * 8;
    const int mbase = mt * 128 + (wave >> 1) * 64;
    const int nbase = nt * 128 + (wave & 1) * 64;

    f32x4 acc[4][4];
#pragma unroll
    for (int f = 0; f < 4; f++)
#pragma unroll
        for (int g = 0; g < 4; g++) acc[f][g] = (f32x4)(0.0f);

#pragma unroll 2
    for (int k0 = 0; k0 < DTRANK; k0 += 32) {
        bf16x8 a[4], b[4];
#pragma unroll
        for (int f = 0; f < 4; f++)
            a[f] = *(const bf16x8*)&dtr[(size_t)(mbase + f * 16 + r) * DTRANK + k0 + kq];
#pragma unroll
        for (int g = 0; g < 4; g++)
            b[g] = *(const bf16x8*)&Wdtb[(size_t)(nbase + g * 16 + r) * DTRANK + k0 + kq];
#pragma unroll
        for (int f = 0; f < 4; f++)
#pragma unroll
            for (int g = 0; g < 4; g++)
                acc[f][g] = __builtin_amdgcn_mfma_f32_16x16x32_bf16(a[f], b[g], acc[f][g], 0, 0, 0);
    }

#pragma unroll
    for (int f = 0; f < 4; f++) {
        const int row0 = mbase + f * 16 + quad * 4;
#pragma unroll
        for (int g = 0; g < 4; g++) {
            const int col = nbase + g * 16 + r;
            const float bv = bdt[col];
#pragma unroll
            for (int i = 0; i < 4; i++) {
                const float z = acc[f][g][i] + bv;
                const float sp = (z > 20.0f) ? z : log1pf(__expf(z));
                delta[(size_t)(row0 + i) * DI + col] = sp;
            }
        }
    }
}

// ---------------------------------------------------------------------------
// Scan pass 1: per (b, chunk, d) chunk summary (P = prod dA, H = h_end), h=0.
// grid: BSZ*NC*8 = 512 blocks x 256 threads.
// ---------------------------------------------------------------------------
__global__ __launch_bounds__(256) void scan_pass1(const float* __restrict__ x,
                                                  const float* __restrict__ delta,
                                                  const float* __restrict__ xdbl,
                                                  const float* __restrict__ Alog,
                                                  float* __restrict__ Pb,
                                                  float* __restrict__ Hb) {
    const int bi   = blockIdx.x;
    const int b    = bi >> 8;
    const int c    = (bi >> 3) & 31;
    const int dblk = bi & 7;
    const int d    = dblk * 256 + threadIdx.x;

    float A[8], h[8], P[8];
#pragma unroll
    for (int n = 0; n < 8; n++) {
        A[n] = -__expf(Alog[d * 8 + n]);
        h[n] = 0.f;
        P[n] = 1.f;
    }
    const int l0 = c * CL;
#pragma unroll 4
    for (int l = l0; l < l0 + CL; l++) {
        const size_t row = (size_t)b * LSEQ + l;
        const float dl = delta[row * DI + d];
        const float xv = x[row * DI + d];
        const float du = dl * xv;
        const float* Bp = &xdbl[row * KXP + DTRANK];
        const float4 B0 = *(const float4*)Bp;
        const float4 B1 = *(const float4*)(Bp + 4);
        const float Bn[8] = {B0.x, B0.y, B0.z, B0.w, B1.x, B1.y, B1.z, B1.w};
#pragma unroll
        for (int n = 0; n < 8; n++) {
            const float dA = __expf(dl * A[n]);
            h[n] = dA * h[n] + du * Bn[n];
            P[n] *= dA;
        }
    }
    const size_t base = ((size_t)(b * NC + c) * DI + d) * 8;
    *(float4*)&Pb[base]     = make_float4(P[0], P[1], P[2], P[3]);
    *(float4*)&Pb[base + 4] = make_float4(P[4], P[5], P[6], P[7]);
    *(float4*)&Hb[base]     = make_float4(h[0], h[1], h[2], h[3]);
    *(float4*)&Hb[base + 4] = make_float4(h[4], h[5], h[6], h[7]);
}

// ---------------------------------------------------------------------------
// Scan pass 2: combine NC chunk summaries -> h0 entering each chunk.
// One thread per (b, d, n) scalar chain: 32768 threads, coalesced.
// ---------------------------------------------------------------------------
__global__ __launch_bounds__(256) void scan_pass2(const float* __restrict__ Pb,
                                                  const float* __restrict__ Hb,
                                                  float* __restrict__ h0) {
    const int t   = blockIdx.x * 256 + threadIdx.x;  // 0..32767
    const int b   = t >> 14;
    const int rem = t & 16383;                       // d*8+n
    float h = 0.f;
#pragma unroll 4
    for (int c = 0; c < NC; c++) {
        const size_t base = (size_t)(b * NC + c) * (DI * 8) + rem;
        h0[base] = h;
        h = Pb[base] * h + Hb[base];
    }
}

// ---------------------------------------------------------------------------
// Scan pass 3: re-scan each chunk from h0, produce y.
// ---------------------------------------------------------------------------
__global__ __launch_bounds__(256) void scan_pass3(const float* __restrict__ x,
                                                  const float* __restrict__ delta,
                                                  const float* __restrict__ xdbl,
                                                  const float* __restrict__ Alog,
                                                  const float* __restrict__ Dp,
                                                  const float* __restrict__ h0,
                                                  float* __restrict__ y) {
    const int bi   = blockIdx.x;
    const int b    = bi >> 8;
    const int c    = (bi >> 3) & 31;
    const int dblk = bi & 7;
    const int d    = dblk * 256 + threadIdx.x;

    float A[8], h[8];
    const size_t hbase = ((size_t)(b * NC + c) * DI + d) * 8;
    const float4 h0a = *(const float4*)&h0[hbase];
    const float4 h0b = *(const float4*)&h0[hbase + 4];
    h[0] = h0a.x; h[1] = h0a.y; h[2] = h0a.z; h[3] = h0a.w;
    h[4] = h0b.x; h[5] = h0b.y; h[6] = h0b.z; h[7] = h0b.w;
#pragma unroll
    for (int n = 0; n < 8; n++) A[n] = -__expf(Alog[d * 8 + n]);
    const float Dpar = Dp[d];

    const int l0 = c * CL;
#pragma unroll 4
    for (int l = l0; l < l0 + CL; l++) {
        const size_t row = (size_t)b * LSEQ + l;
        const float dl = delta[row * DI + d];
        const float xv = x[row * DI + d];
        const float du = dl * xv;
        const float* Bp = &xdbl[row * KXP + DTRANK];
        const float4 B0 = *(const float4*)Bp;
        const float4 B1 = *(const float4*)(Bp + 4);
        const float4 C0 = *(const float4*)(Bp + 8);
        const float4 C1 = *(const float4*)(Bp + 12);
        const float Bn[8] = {B0.x, B0.y, B0.z, B0.w, B1.x, B1.y, B1.z, B1.w};
        const float Cn[8] = {C0.x, C0.y, C0.z, C0.w, C1.x, C1.y, C1.z, C1.w};
        float yv = 0.f;
#pragma unroll
        for (int n = 0; n < 8; n++) {
            const float dA = __expf(dl * A[n]);
            h[n] = dA * h[n] + du * Bn[n];
            yv += h[n] * Cn[n];
        }
        yv += xv * Dpar;
        y[row * DI + d] = yv;
    }
}

// ---------------------------------------------------------------------------
extern "C" void kernel_launch(void* const* d_in, const int* in_sizes, int n_in,
                              void* d_out, int out_size, void* d_ws, size_t ws_size,
                              hipStream_t stream) {
    const float* x    = (const float*)d_in[0];
    const float* Wx   = (const float*)d_in[1];
    const float* Wdt  = (const float*)d_in[2];
    const float* bdt  = (const float*)d_in[3];
    const float* Alog = (const float*)d_in[4];
    const float* Dp   = (const float*)d_in[5];
    float* y = (float*)d_out;

    // Workspace layout. Aliasing: [part | xb] is dead after gemm1/reduce1;
    // delta (written by gemm2, later) reuses that region.
    //   part  : 4*4096*288           = 4,718,592 f   (f-offset 0)
    //   xb    : 8,388,608 bf16       = 4,194,304 f   (f-offset 4,718,592)
    //   delta : 8,388,608 f  (alias of [0 .. 8,912,896))
    //   xdbl  : 1,114,112 f          (f-offset 8,912,896)
    //   Pb/Hb/h0 : 3 x 1,048,576 f   (BSZ*NC*DI*8)
    //   Wxb   : 589,824 bf16
    //   Wdtb  : 524,288 bf16
    //   dtr   : 1,048,576 bf16
    float* ws = (float*)d_ws;
    float* part  = ws;
    unsigned short* xb = (unsigned short*)(ws + 4718592);
    float* delta = ws;                                  // alias (after reduce1)
    float* xdbl  = ws + 8912896;
    float* Pb    = xdbl + 1114112;
    float* Hb    = Pb + 1048576;
    float* h0    = Hb + 1048576;
    unsigned short* Wxb  = (unsigned short*)(h0 + 1048576);
    unsigned short* Wdtb = Wxb + (size_t)NWXP;
    unsigned short* dtr  = Wdtb + (size_t)NWDT;

    dim3 blk(256);
    hipLaunchKernelGGL(convert_kern, dim3((NX + NWXP + NWDT) / 4 / 256), blk, 0, stream,
                       x, Wx, Wdt, xb, Wxb, Wdtb);
    hipLaunchKernelGGL(gemm1_mfma, dim3(64, KSPLIT), blk, 0, stream, xb, Wxb, part);
    hipLaunchKernelGGL(reduce1, dim3(4096 * 72 / 256), blk, 0, stream, part, xdbl, dtr);
    hipLaunchKernelGGL(gemm2_mfma, dim3(16, 32), blk, 0, stream, dtr, Wdtb, bdt, delta);
    hipLaunchKernelGGL(scan_pass1, dim3(BSZ * NC * 8), blk, 0, stream, x, delta, xdbl, Alog, Pb, Hb);
    hipLaunchKernelGGL(scan_pass2, dim3(128), blk, 0, stream, Pb, Hb, h0);
    hipLaunchKernelGGL(scan_pass3, dim3(BSZ * NC * 8), blk, 0, stream, x, delta, xdbl, Alog, Dp, h0, y);
}

// Round 4
// 200.003 us; speedup vs baseline: 1.9913x; 1.1785x over previous
//
#include <hip/hip_runtime.h>
#include <math.h>

// Problem constants
#define BSZ    2
#define LSEQ   2048
#define DI     2048
#define DSTATE 8
#define DTRANK 256
#define KXP    (DTRANK + 2 * DSTATE)   // 272
#define NPAD   288                     // KXP padded to 18*16 for MFMA tiles
#define NC     64                      // scan chunks
#define CL     (LSEQ / NC)             // 32
#define KSPLIT 4

#define NWXP (288u * 2048u)            // 589824 (padded)
#define NWX  (272u * 2048u)            // 557056 (real)
#define NWDT (2048u * 256u)            // 524288

typedef __attribute__((ext_vector_type(8))) short bf16x8;
typedef __attribute__((ext_vector_type(4))) float f32x4;

static __device__ __forceinline__ unsigned short f2bf(float f) {
    unsigned u = __float_as_uint(f);
    u += 0x7fff + ((u >> 16) & 1);   // round-to-nearest-even
    return (unsigned short)(u >> 16);
}

static __device__ __forceinline__ float softplus_fast(float z) {
    // softplus(z) = max(z,0) + log(1 + exp(-|z|)); hw exp/log
    const float e = __expf(-fabsf(z));
    return fmaxf(z, 0.0f) + __logf(1.0f + e);
}

// ---------------------------------------------------------------------------
// Convert weight matrices to bf16: W_xproj (272x2048 -> padded 288x2048) and
// W_dt (2048x256). 4 elems/thread. (x stays fp32; gemm1 converts in-register.)
// ---------------------------------------------------------------------------
__global__ __launch_bounds__(256) void convert_w(const float* __restrict__ Wx,
                                                 const float* __restrict__ Wdt,
                                                 unsigned short* __restrict__ Wxb,
                                                 unsigned short* __restrict__ Wdtb) {
    const unsigned tid = blockIdx.x * 256 + threadIdx.x;
    const unsigned i4 = tid * 4;
    float4 v;
    unsigned short* dst;
    unsigned j;
    if (i4 < NWXP) {
        j = i4;
        v = (j < NWX) ? *(const float4*)&Wx[j] : make_float4(0.f, 0.f, 0.f, 0.f);
        dst = Wxb;
    } else {
        j = i4 - NWXP;
        if (j >= NWDT) return;
        v = *(const float4*)&Wdt[j];
        dst = Wdtb;
    }
    ushort4 o;
    o.x = f2bf(v.x); o.y = f2bf(v.y); o.z = f2bf(v.z); o.w = f2bf(v.w);
    *(ushort4*)&dst[j] = o;
}

// ---------------------------------------------------------------------------
// GEMM1 (MFMA, split-K): part[ks][4096][288] = x[., ks-chunk] @ Wxb^T
// x read fp32 and converted in-register. grid (64 Mtiles, 4 Ksplits).
// 4 waves, each 16 rows x 288 cols (1x18 frags); B direct from global (L2).
// ---------------------------------------------------------------------------
__global__ __launch_bounds__(256, 1) void gemm1_mfma(const float* __restrict__ x,
                                                     const unsigned short* __restrict__ Wxb,
                                                     float* __restrict__ part) {
    const int mt   = blockIdx.x;   // 0..63
    const int ks   = blockIdx.y;   // 0..3
    const int wave = threadIdx.x >> 6;
    const int lane = threadIdx.x & 63;
    const int quad = lane >> 4;
    const int r    = lane & 15;
    const int kq   = quad * 8;
    const int mbase = mt * 64 + wave * 16;
    const size_t arow = (size_t)(mbase + r) * DI;   // fp32 row
    const size_t brow = (size_t)r * DI;

    f32x4 acc[18];
#pragma unroll
    for (int n = 0; n < 18; n++) acc[n] = (f32x4)(0.0f);

    const int kbeg = ks * (DI / KSPLIT);
#pragma unroll 2
    for (int k0 = kbeg; k0 < kbeg + DI / KSPLIT; k0 += 32) {
        const float4 u0 = *(const float4*)&x[arow + k0 + kq];
        const float4 u1 = *(const float4*)&x[arow + k0 + kq + 4];
        bf16x8 a;
        a[0] = (short)f2bf(u0.x); a[1] = (short)f2bf(u0.y);
        a[2] = (short)f2bf(u0.z); a[3] = (short)f2bf(u0.w);
        a[4] = (short)f2bf(u1.x); a[5] = (short)f2bf(u1.y);
        a[6] = (short)f2bf(u1.z); a[7] = (short)f2bf(u1.w);
#pragma unroll
        for (int nf = 0; nf < 18; nf++) {
            const bf16x8 b = *(const bf16x8*)&Wxb[brow + nf * (16 * DI) + k0 + kq];
            acc[nf] = __builtin_amdgcn_mfma_f32_16x16x32_bf16(a, b, acc[nf], 0, 0, 0);
        }
    }

    float* p = part + (size_t)ks * 4096 * NPAD;
    const int row0 = mbase + quad * 4;
#pragma unroll
    for (int nf = 0; nf < 18; nf++) {
        const int col = nf * 16 + r;
#pragma unroll
        for (int i = 0; i < 4; i++)
            p[(size_t)(row0 + i) * NPAD + col] = acc[nf][i];
    }
}

// ---------------------------------------------------------------------------
// Reduce split-K partials -> xdbl fp32 [4096][272]; also emit dtr bf16
// [4096][256] for GEMM2. 4 cols/thread.
// ---------------------------------------------------------------------------
__global__ __launch_bounds__(256) void reduce1(const float* __restrict__ part,
                                               float* __restrict__ xdbl,
                                               unsigned short* __restrict__ dtr) {
    const int tid = blockIdx.x * 256 + threadIdx.x;  // 4096*72
    const int row = tid / 72;
    const int c4  = (tid - row * 72) * 4;
    float4 s = make_float4(0.f, 0.f, 0.f, 0.f);
#pragma unroll
    for (int ks = 0; ks < KSPLIT; ks++) {
        const float4 v = *(const float4*)&part[(size_t)ks * 4096 * NPAD + (size_t)row * NPAD + c4];
        s.x += v.x; s.y += v.y; s.z += v.z; s.w += v.w;
    }
    if (c4 < KXP) *(float4*)&xdbl[(size_t)row * KXP + c4] = s;
    if (c4 < DTRANK) {
        ushort4 o;
        o.x = f2bf(s.x); o.y = f2bf(s.y); o.z = f2bf(s.z); o.w = f2bf(s.w);
        *(ushort4*)&dtr[(size_t)row * DTRANK + c4] = o;
    }
}

// ---------------------------------------------------------------------------
// GEMM2 (MFMA, LDS-staged): delta[4096][2048] = softplus(dtr @ Wdtb^T + b_dt).
// K=256, BK=32. 128x128 block tile, 4 waves each 64x64 (4x4 frags).
// LDS row stride padded 32->40 shorts (80 B) to break bank conflicts.
// ---------------------------------------------------------------------------
#define G2RS 40
__global__ __launch_bounds__(256, 2) void gemm2_mfma(const unsigned short* __restrict__ dtr,
                                                     const unsigned short* __restrict__ Wdtb,
                                                     const float* __restrict__ bdt,
                                                     float* __restrict__ delta) {
    __shared__ __align__(16) unsigned short As[128 * G2RS];
    __shared__ __align__(16) unsigned short Bs[128 * G2RS];
    const int nt   = blockIdx.x;
    const int mt   = blockIdx.y;
    const int t    = threadIdx.x;
    const int wave = t >> 6;
    const int lane = t & 63;
    const int quad = lane >> 4;
    const int r    = lane & 15;
    const int m0 = mt * 128, n0 = nt * 128;
    const int mw = (wave >> 1) * 64, nw = (wave & 1) * 64;

    // staging map: thread t loads 32 B (16 shorts) of one row of A and of B
    const int srow = t >> 1;             // 0..127
    const int sc   = (t & 1) * 16;       // 0 or 16 shorts

    f32x4 acc[4][4];
#pragma unroll
    for (int f = 0; f < 4; f++)
#pragma unroll
        for (int g = 0; g < 4; g++) acc[f][g] = (f32x4)(0.0f);

    for (int k0 = 0; k0 < DTRANK; k0 += 32) {
        const bf16x8 a0 = *(const bf16x8*)&dtr[(size_t)(m0 + srow) * DTRANK + k0 + sc];
        const bf16x8 a1 = *(const bf16x8*)&dtr[(size_t)(m0 + srow) * DTRANK + k0 + sc + 8];
        const bf16x8 b0 = *(const bf16x8*)&Wdtb[(size_t)(n0 + srow) * DTRANK + k0 + sc];
        const bf16x8 b1 = *(const bf16x8*)&Wdtb[(size_t)(n0 + srow) * DTRANK + k0 + sc + 8];
        __syncthreads();   // prev iter's LDS reads done
        *(bf16x8*)&As[srow * G2RS + sc]     = a0;
        *(bf16x8*)&As[srow * G2RS + sc + 8] = a1;
        *(bf16x8*)&Bs[srow * G2RS + sc]     = b0;
        *(bf16x8*)&Bs[srow * G2RS + sc + 8] = b1;
        __syncthreads();   // writes visible

        bf16x8 a[4], b[4];
#pragma unroll
        for (int f = 0; f < 4; f++)
            a[f] = *(const bf16x8*)&As[(mw + f * 16 + r) * G2RS + quad * 8];
#pragma unroll
        for (int g = 0; g < 4; g++)
            b[g] = *(const bf16x8*)&Bs[(nw + g * 16 + r) * G2RS + quad * 8];
#pragma unroll
        for (int f = 0; f < 4; f++)
#pragma unroll
            for (int g = 0; g < 4; g++)
                acc[f][g] = __builtin_amdgcn_mfma_f32_16x16x32_bf16(a[f], b[g], acc[f][g], 0, 0, 0);
    }

#pragma unroll
    for (int f = 0; f < 4; f++) {
        const int row0 = m0 + mw + f * 16 + quad * 4;
#pragma unroll
        for (int g = 0; g < 4; g++) {
            const int col = n0 + nw + g * 16 + r;
            const float bv = bdt[col];
#pragma unroll
            for (int i = 0; i < 4; i++)
                delta[(size_t)(row0 + i) * DI + col] = softplus_fast(acc[f][g][i] + bv);
        }
    }
}

// ---------------------------------------------------------------------------
// Scan pass 1: per (b, chunk, d) chunk summary (P = prod dA, H = h_end), h=0.
// grid: BSZ*NC*8 = 1024 blocks. B rows staged in LDS (broadcast reads).
// ---------------------------------------------------------------------------
__global__ __launch_bounds__(256) void scan_pass1(const float* __restrict__ x,
                                                  const float* __restrict__ delta,
                                                  const float* __restrict__ xdbl,
                                                  const float* __restrict__ Alog,
                                                  float* __restrict__ Pb,
                                                  float* __restrict__ Hb) {
    __shared__ __align__(16) float Ls[CL * 8];     // B rows for this chunk
    const int bi   = blockIdx.x;
    const int b    = bi >> 9;
    const int c    = (bi >> 3) & 63;
    const int dblk = bi & 7;
    const int d    = dblk * 256 + threadIdx.x;
    const int l0   = c * CL;
    const size_t row0 = (size_t)b * LSEQ + l0;

    if (threadIdx.x < CL * 2) {
        const int l = threadIdx.x >> 1, part = (threadIdx.x & 1) * 4;
        const float4 v = *(const float4*)&xdbl[(row0 + l) * KXP + DTRANK + part];
        *(float4*)&Ls[l * 8 + part] = v;
    }

    float A[8], h[8], P[8];
#pragma unroll
    for (int n = 0; n < 8; n++) {
        A[n] = -__expf(Alog[d * 8 + n]);
        h[n] = 0.f;
        P[n] = 1.f;
    }
    __syncthreads();

#pragma unroll 4
    for (int l = 0; l < CL; l++) {
        const size_t row = row0 + l;
        const float dl = delta[row * DI + d];
        const float xv = x[row * DI + d];
        const float du = dl * xv;
#pragma unroll
        for (int n = 0; n < 8; n++) {
            const float dA = __expf(dl * A[n]);
            h[n] = dA * h[n] + du * Ls[l * 8 + n];
            P[n] *= dA;
        }
    }
    const size_t base = ((size_t)(b * NC + c) * DI + d) * 8;
    *(float4*)&Pb[base]     = make_float4(P[0], P[1], P[2], P[3]);
    *(float4*)&Pb[base + 4] = make_float4(P[4], P[5], P[6], P[7]);
    *(float4*)&Hb[base]     = make_float4(h[0], h[1], h[2], h[3]);
    *(float4*)&Hb[base + 4] = make_float4(h[4], h[5], h[6], h[7]);
}

// ---------------------------------------------------------------------------
// Scan pass 2: combine NC chunk summaries -> h0 entering each chunk.
// One thread per (b, d, n) scalar chain: 32768 threads, coalesced.
// ---------------------------------------------------------------------------
__global__ __launch_bounds__(256) void scan_pass2(const float* __restrict__ Pb,
                                                  const float* __restrict__ Hb,
                                                  float* __restrict__ h0) {
    const int t   = blockIdx.x * 256 + threadIdx.x;  // 0..32767
    const int b   = t >> 14;
    const int rem = t & 16383;                       // d*8+n
    float h = 0.f;
#pragma unroll 4
    for (int c = 0; c < NC; c++) {
        const size_t base = (size_t)(b * NC + c) * (DI * 8) + rem;
        h0[base] = h;
        h = Pb[base] * h + Hb[base];
    }
}

// ---------------------------------------------------------------------------
// Scan pass 3: re-scan each chunk from h0, produce y. B/C staged in LDS.
// ---------------------------------------------------------------------------
__global__ __launch_bounds__(256) void scan_pass3(const float* __restrict__ x,
                                                  const float* __restrict__ delta,
                                                  const float* __restrict__ xdbl,
                                                  const float* __restrict__ Alog,
                                                  const float* __restrict__ Dp,
                                                  const float* __restrict__ h0,
                                                  float* __restrict__ y) {
    __shared__ __align__(16) float Ls[CL * 16];    // B and C rows
    const int bi   = blockIdx.x;
    const int b    = bi >> 9;
    const int c    = (bi >> 3) & 63;
    const int dblk = bi & 7;
    const int d    = dblk * 256 + threadIdx.x;
    const int l0   = c * CL;
    const size_t row0 = (size_t)b * LSEQ + l0;

    if (threadIdx.x < CL * 4) {
        const int l = threadIdx.x >> 2, part = (threadIdx.x & 3) * 4;
        const float4 v = *(const float4*)&xdbl[(row0 + l) * KXP + DTRANK + part];
        *(float4*)&Ls[l * 16 + part] = v;
    }

    float A[8], h[8];
    const size_t hbase = ((size_t)(b * NC + c) * DI + d) * 8;
    const float4 h0a = *(const float4*)&h0[hbase];
    const float4 h0b = *(const float4*)&h0[hbase + 4];
    h[0] = h0a.x; h[1] = h0a.y; h[2] = h0a.z; h[3] = h0a.w;
    h[4] = h0b.x; h[5] = h0b.y; h[6] = h0b.z; h[7] = h0b.w;
#pragma unroll
    for (int n = 0; n < 8; n++) A[n] = -__expf(Alog[d * 8 + n]);
    const float Dpar = Dp[d];
    __syncthreads();

#pragma unroll 4
    for (int l = 0; l < CL; l++) {
        const size_t row = row0 + l;
        const float dl = delta[row * DI + d];
        const float xv = x[row * DI + d];
        const float du = dl * xv;
        float yv = 0.f;
#pragma unroll
        for (int n = 0; n < 8; n++) {
            const float dA = __expf(dl * A[n]);
            h[n] = dA * h[n] + du * Ls[l * 16 + n];
            yv += h[n] * Ls[l * 16 + 8 + n];
        }
        yv += xv * Dpar;
        y[row * DI + d] = yv;
    }
}

// ---------------------------------------------------------------------------
extern "C" void kernel_launch(void* const* d_in, const int* in_sizes, int n_in,
                              void* d_out, int out_size, void* d_ws, size_t ws_size,
                              hipStream_t stream) {
    const float* x    = (const float*)d_in[0];
    const float* Wx   = (const float*)d_in[1];
    const float* Wdt  = (const float*)d_in[2];
    const float* bdt  = (const float*)d_in[3];
    const float* Alog = (const float*)d_in[4];
    const float* Dp   = (const float*)d_in[5];
    float* y = (float*)d_out;

    // Workspace (floats unless noted). delta aliases part (dead after reduce1).
    //   part  : 4*4096*288 = 4,718,592 f   @ 0
    //   delta : 8,388,608 f                @ 0   (alias)
    //   xdbl  : 1,114,112 f                @ 8,388,608
    //   Pb/Hb/h0 : 3 x 2,097,152 f  (BSZ*NC*DI*8, NC=64)
    //   Wxb (589,824 us) | Wdtb (524,288 us) | dtr (1,048,576 us)
    // total ~67.5 MB
    float* ws    = (float*)d_ws;
    float* part  = ws;
    float* delta = ws;                       // alias (after reduce1)
    float* xdbl  = ws + 8388608;
    float* Pb    = xdbl + 1114112;
    float* Hb    = Pb + 2097152;
    float* h0    = Hb + 2097152;
    unsigned short* Wxb  = (unsigned short*)(h0 + 2097152);
    unsigned short* Wdtb = Wxb + (size_t)NWXP;
    unsigned short* dtr  = Wdtb + (size_t)NWDT;

    dim3 blk(256);
    hipLaunchKernelGGL(convert_w, dim3((NWXP + NWDT) / 4 / 256), blk, 0, stream,
                       Wx, Wdt, Wxb, Wdtb);
    hipLaunchKernelGGL(gemm1_mfma, dim3(64, KSPLIT), blk, 0, stream, x, Wxb, part);
    hipLaunchKernelGGL(reduce1, dim3(4096 * 72 / 256), blk, 0, stream, part, xdbl, dtr);
    hipLaunchKernelGGL(gemm2_mfma, dim3(16, 32), blk, 0, stream, dtr, Wdtb, bdt, delta);
    hipLaunchKernelGGL(scan_pass1, dim3(BSZ * NC * 8), blk, 0, stream, x, delta, xdbl, Alog, Pb, Hb);
    hipLaunchKernelGGL(scan_pass2, dim3(128), blk, 0, stream, Pb, Hb, h0);
    hipLaunchKernelGGL(scan_pass3, dim3(BSZ * NC * 8), blk, 0, stream, x, delta, xdbl, Alog, Dp, h0, y);
}